// Round 1
// baseline (59.477 us; speedup 1.0000x reference)
//
#include <hip/hip_runtime.h>
#include <hip/hip_bf16.h>

// z[b,i] = mu[a_b, i] + sum_{j<=i} L[a_b, i, j] * eps[b, j]
// B = 1048576, A = 65536, D = 8
__global__ __launch_bounds__(256) void lv_kernel(
    const int* __restrict__ ann,        // [B] int32
    const float* __restrict__ mu,       // [A,8]
    const float* __restrict__ L,        // [A,8,8]
    const float* __restrict__ eps,      // [B,8]
    float* __restrict__ out,            // [B,8]
    int B)
{
    int b = blockIdx.x * blockDim.x + threadIdx.x;
    if (b >= B) return;

    const int a = ann[b];

    // eps[b, 0..7] — coalesced-ish (contiguous 2KB span per wave)
    const float4* epsv = reinterpret_cast<const float4*>(eps + (size_t)b * 8);
    const float4 e0 = epsv[0];
    const float4 e1 = epsv[1];
    const float e[8] = {e0.x, e0.y, e0.z, e0.w, e1.x, e1.y, e1.z, e1.w};

    // mu[a, 0..7] — gathered
    const float4* muv = reinterpret_cast<const float4*>(mu + (size_t)a * 8);
    const float4 m0 = muv[0];
    const float4 m1 = muv[1];
    float z[8] = {m0.x, m0.y, m0.z, m0.w, m1.x, m1.y, m1.z, m1.w};

    // L[a, i, j] — gathered. Rows 0..3 only need j<=3 (one float4);
    // rows 4..7 need j<=7 (two float4s). 12 float4 gathers total.
    const float4* Lv = reinterpret_cast<const float4*>(L + (size_t)a * 64);

    #pragma unroll
    for (int i = 0; i < 4; ++i) {
        const float4 r0 = Lv[i * 2];
        const float r[4] = {r0.x, r0.y, r0.z, r0.w};
        #pragma unroll
        for (int j = 0; j <= i; ++j) z[i] += r[j] * e[j];
    }
    #pragma unroll
    for (int i = 4; i < 8; ++i) {
        const float4 r0 = Lv[i * 2];
        const float4 r1 = Lv[i * 2 + 1];
        const float r[8] = {r0.x, r0.y, r0.z, r0.w, r1.x, r1.y, r1.z, r1.w};
        #pragma unroll
        for (int j = 0; j <= i; ++j) z[i] += r[j] * e[j];
    }

    float4* outv = reinterpret_cast<float4*>(out + (size_t)b * 8);
    outv[0] = make_float4(z[0], z[1], z[2], z[3]);
    outv[1] = make_float4(z[4], z[5], z[6], z[7]);
}

extern "C" void kernel_launch(void* const* d_in, const int* in_sizes, int n_in,
                              void* d_out, int out_size, void* d_ws, size_t ws_size,
                              hipStream_t stream) {
    const int*   ann = (const int*)d_in[0];    // annotator [B]
    const float* mu  = (const float*)d_in[1];  // posterior_mu [A,8]
    const float* L   = (const float*)d_in[2];  // posterior_covtril [A,8,8]
    const float* eps = (const float*)d_in[3];  // eps [B,8]
    float* out = (float*)d_out;

    const int B = in_sizes[0];
    const int threads = 256;
    const int blocks = (B + threads - 1) / threads;
    lv_kernel<<<blocks, threads, 0, stream>>>(ann, mu, L, eps, out, B);
}

// Round 3
// 55.685 us; speedup vs baseline: 1.0681x; 1.0681x over previous
//
#include <hip/hip_runtime.h>
#include <hip/hip_bf16.h>
#include <hip/hip_fp16.h>

// z[b,i] = mu[a_b, i] + sum_{j<=i} L[a_b, i, j] * eps[b, j]
// B = 1048576, A = 65536, D = 8
//
// Strategy: random gathers from an 18 MB fp32 table are the bottleneck
// (5 random 64B lines/thread). Compact tables to fp16 (9 MB, 3 lines/thread)
// in d_ws each call, keep table reads cached, stream eps/ann/out with
// nontemporal hints so they don't evict the table from L2.

#define A_CNT 65536

typedef float  f32x4 __attribute__((ext_vector_type(4)));
typedef float  f32x2 __attribute__((ext_vector_type(2)));
typedef _Float16 f16x8 __attribute__((ext_vector_type(8)));
typedef _Float16 f16x4 __attribute__((ext_vector_type(4)));

// ---- fp32 -> fp16 conversion, 8 floats per thread ----
__global__ __launch_bounds__(256) void conv_kernel(
    const float* __restrict__ src, _Float16* __restrict__ dst, int n8)
{
    int i = blockIdx.x * blockDim.x + threadIdx.x;
    if (i >= n8) return;
    const f32x4* s = reinterpret_cast<const f32x4*>(src) + (size_t)i * 2;
    f32x4 v0 = __builtin_nontemporal_load(s);
    f32x4 v1 = __builtin_nontemporal_load(s + 1);
    f16x8 h;
    #pragma unroll
    for (int j = 0; j < 4; ++j) h[j] = (_Float16)v0[j];
    #pragma unroll
    for (int j = 0; j < 4; ++j) h[4 + j] = (_Float16)v1[j];
    __builtin_nontemporal_store(h, reinterpret_cast<f16x8*>(dst) + i);
}

// ---- main kernel: fp16 gather tables ----
__global__ __launch_bounds__(256) void lv_kernel_h(
    const int* __restrict__ ann,             // [B]
    const _Float16* __restrict__ muh,        // [A,8]  16B/row
    const _Float16* __restrict__ Lh,         // [A,64] 128B/row
    const float* __restrict__ eps,           // [B,8]
    float* __restrict__ out,                 // [B,8]
    int B)
{
    int b = blockIdx.x * blockDim.x + threadIdx.x;
    if (b >= B) return;

    const int a = __builtin_nontemporal_load(ann + b);

    const f32x4* epsv = reinterpret_cast<const f32x4*>(eps + (size_t)b * 8);
    const f32x4 e0 = __builtin_nontemporal_load(epsv);
    const f32x4 e1 = __builtin_nontemporal_load(epsv + 1);
    const float e[8] = {e0[0], e0[1], e0[2], e0[3], e1[0], e1[1], e1[2], e1[3]};

    // mu row: 8 halfs = 16B, one line (cached load)
    const f16x8 m = *reinterpret_cast<const f16x8*>(muh + (size_t)a * 8);
    float z[8];
    #pragma unroll
    for (int i = 0; i < 8; ++i) z[i] = (float)m[i];

    const _Float16* Lrow = Lh + (size_t)a * 64;

    // rows 0..3: need j<=3 -> 8B load
    #pragma unroll
    for (int i = 0; i < 4; ++i) {
        const f16x4 r = *reinterpret_cast<const f16x4*>(Lrow + i * 8);
        #pragma unroll
        for (int j = 0; j <= i; ++j) z[i] += (float)r[j] * e[j];
    }
    // rows 4..7: need j<=7 -> 16B load
    #pragma unroll
    for (int i = 4; i < 8; ++i) {
        const f16x8 r = *reinterpret_cast<const f16x8*>(Lrow + i * 8);
        #pragma unroll
        for (int j = 0; j <= i; ++j) z[i] += (float)r[j] * e[j];
    }

    f32x4* outv = reinterpret_cast<f32x4*>(out + (size_t)b * 8);
    f32x4 o0 = {z[0], z[1], z[2], z[3]};
    f32x4 o1 = {z[4], z[5], z[6], z[7]};
    __builtin_nontemporal_store(o0, outv);
    __builtin_nontemporal_store(o1, outv + 1);
}

// ---- fallback: original fp32 kernel (if ws too small) ----
__global__ __launch_bounds__(256) void lv_kernel_f32(
    const int* __restrict__ ann,
    const float* __restrict__ mu,
    const float* __restrict__ L,
    const float* __restrict__ eps,
    float* __restrict__ out,
    int B)
{
    int b = blockIdx.x * blockDim.x + threadIdx.x;
    if (b >= B) return;
    const int a = ann[b];
    const f32x4* epsv = reinterpret_cast<const f32x4*>(eps + (size_t)b * 8);
    const f32x4 e0 = epsv[0];
    const f32x4 e1 = epsv[1];
    const float e[8] = {e0[0], e0[1], e0[2], e0[3], e1[0], e1[1], e1[2], e1[3]};
    const f32x4* muv = reinterpret_cast<const f32x4*>(mu + (size_t)a * 8);
    const f32x4 m0 = muv[0];
    const f32x4 m1 = muv[1];
    float z[8] = {m0[0], m0[1], m0[2], m0[3], m1[0], m1[1], m1[2], m1[3]};
    const f32x4* Lv = reinterpret_cast<const f32x4*>(L + (size_t)a * 64);
    #pragma unroll
    for (int i = 0; i < 4; ++i) {
        const f32x4 r0 = Lv[i * 2];
        #pragma unroll
        for (int j = 0; j <= i; ++j) z[i] += r0[j] * e[j];
    }
    #pragma unroll
    for (int i = 4; i < 8; ++i) {
        const f32x4 r0 = Lv[i * 2];
        const f32x4 r1 = Lv[i * 2 + 1];
        const float r[8] = {r0[0], r0[1], r0[2], r0[3], r1[0], r1[1], r1[2], r1[3]};
        #pragma unroll
        for (int j = 0; j <= i; ++j) z[i] += r[j] * e[j];
    }
    f32x4* outv = reinterpret_cast<f32x4*>(out + (size_t)b * 8);
    f32x4 o0 = {z[0], z[1], z[2], z[3]};
    f32x4 o1 = {z[4], z[5], z[6], z[7]};
    outv[0] = o0;
    outv[1] = o1;
}

extern "C" void kernel_launch(void* const* d_in, const int* in_sizes, int n_in,
                              void* d_out, int out_size, void* d_ws, size_t ws_size,
                              hipStream_t stream) {
    const int*   ann = (const int*)d_in[0];    // annotator [B]
    const float* mu  = (const float*)d_in[1];  // posterior_mu [A,8]
    const float* L   = (const float*)d_in[2];  // posterior_covtril [A,8,8]
    const float* eps = (const float*)d_in[3];  // eps [B,8]
    float* out = (float*)d_out;

    const int B = in_sizes[0];
    const int threads = 256;
    const int blocks = (B + threads - 1) / threads;

    // ws layout: [ muh: A*8 halfs = 1 MB ][ Lh: A*64 halfs = 8 MB ]
    const size_t mu_bytes = (size_t)A_CNT * 8 * sizeof(_Float16);    // 1 MiB
    const size_t L_bytes  = (size_t)A_CNT * 64 * sizeof(_Float16);   // 8 MiB
    if (ws_size >= mu_bytes + L_bytes) {
        _Float16* muh = (_Float16*)d_ws;
        _Float16* Lh  = (_Float16*)((char*)d_ws + mu_bytes);
        {   // convert mu: A*8 floats = 512K floats -> 64K threads
            int n8 = A_CNT * 8 / 8;
            conv_kernel<<<(n8 + 255) / 256, 256, 0, stream>>>(mu, muh, n8);
        }
        {   // convert L: A*64 floats = 4M floats -> 512K threads
            int n8 = A_CNT * 64 / 8;
            conv_kernel<<<(n8 + 255) / 256, 256, 0, stream>>>(L, Lh, n8);
        }
        lv_kernel_h<<<blocks, threads, 0, stream>>>(ann, muh, Lh, eps, out, B);
    } else {
        lv_kernel_f32<<<blocks, threads, 0, stream>>>(ann, mu, L, eps, out, B);
    }
}

// Round 4
// 54.410 us; speedup vs baseline: 1.0931x; 1.0234x over previous
//
#include <hip/hip_runtime.h>
#include <hip/hip_bf16.h>
#include <hip/hip_fp16.h>

// z[b,i] = mu[a_b, i] + sum_{j<=i} L[a_b, i, j] * eps[b, j]
// B = 1048576, A = 65536, D = 8
//
// Round-4 strategy: txn-rate bound. Pack mu+tril(L) into one 128B fp16
// record per annotator. Wave gathers 64 records COOPERATIVELY (8 lanes x
// 16B chunks per record -> 16 lines/inst instead of 64), stages into LDS
// (XOR-swizzled chunks), each lane reads back its own record and computes.

#define A_CNT 65536

typedef float    f32x4 __attribute__((ext_vector_type(4)));
typedef _Float16 f16x8 __attribute__((ext_vector_type(8)));

// Record layout (64 halfs = 128B), logical half index:
//  h[0..7]   = mu[0..7]
//  h[8+4i+j] = L[i][j]          i=0..3, j=0..3   (h[8..23])
//  h[24+8*(i-4)+j] = L[i][j]    i=4..7, j=0..7   (h[24..55])
//  h[56..63] = pad
// chunk c = halfs [8c .. 8c+7]:
//  ch0 = mu, ch1 = rows0-1, ch2 = rows2-3, ch3..6 = rows4..7, ch7 = pad

__global__ __launch_bounds__(256) void pack_kernel(
    const float* __restrict__ mu,   // [A,8]
    const float* __restrict__ L,    // [A,64]
    _Float16* __restrict__ rec,     // [A,64] halfs
    int A)
{
    int a = blockIdx.x * blockDim.x + threadIdx.x;
    if (a >= A) return;

    const f32x4* muv = reinterpret_cast<const f32x4*>(mu + (size_t)a * 8);
    const f32x4* Lv  = reinterpret_cast<const f32x4*>(L + (size_t)a * 64);
    f32x4 m0 = __builtin_nontemporal_load(muv);
    f32x4 m1 = __builtin_nontemporal_load(muv + 1);
    f32x4 r0 = __builtin_nontemporal_load(Lv + 0);   // L[0][0..3]
    f32x4 r1 = __builtin_nontemporal_load(Lv + 2);   // L[1][0..3]
    f32x4 r2 = __builtin_nontemporal_load(Lv + 4);   // L[2][0..3]
    f32x4 r3 = __builtin_nontemporal_load(Lv + 6);   // L[3][0..3]
    f32x4 r4a = __builtin_nontemporal_load(Lv + 8),  r4b = __builtin_nontemporal_load(Lv + 9);
    f32x4 r5a = __builtin_nontemporal_load(Lv + 10), r5b = __builtin_nontemporal_load(Lv + 11);
    f32x4 r6a = __builtin_nontemporal_load(Lv + 12), r6b = __builtin_nontemporal_load(Lv + 13);
    f32x4 r7a = __builtin_nontemporal_load(Lv + 14), r7b = __builtin_nontemporal_load(Lv + 15);

    f16x8 ch[8];
    #pragma unroll
    for (int j = 0; j < 4; ++j) {
        ch[0][j] = (_Float16)m0[j];  ch[0][4+j] = (_Float16)m1[j];
        ch[1][j] = (_Float16)r0[j];  ch[1][4+j] = (_Float16)r1[j];
        ch[2][j] = (_Float16)r2[j];  ch[2][4+j] = (_Float16)r3[j];
        ch[3][j] = (_Float16)r4a[j]; ch[3][4+j] = (_Float16)r4b[j];
        ch[4][j] = (_Float16)r5a[j]; ch[4][4+j] = (_Float16)r5b[j];
        ch[5][j] = (_Float16)r6a[j]; ch[5][4+j] = (_Float16)r6b[j];
        ch[6][j] = (_Float16)r7a[j]; ch[6][4+j] = (_Float16)r7b[j];
        ch[7][j] = (_Float16)0.f;    ch[7][4+j] = (_Float16)0.f;
    }
    f16x8* o = reinterpret_cast<f16x8*>(rec + (size_t)a * 64);
    #pragma unroll
    for (int c = 0; c < 8; ++c) __builtin_nontemporal_store(ch[c], o + c);
}

__global__ __launch_bounds__(256) void lv_kernel_coop(
    const int* __restrict__ ann,          // [B]
    const _Float16* __restrict__ rec,     // [A,64] halfs, 128B/record
    const float* __restrict__ eps,        // [B,8]
    float* __restrict__ out,              // [B,8]
    int B)
{
    // 4 waves/block, each wave owns 64 batch rows + an 8KB LDS region.
    __shared__ __align__(16) char lds_raw[4 * 64 * 128];

    const int lane = threadIdx.x & 63;
    const int wave = threadIdx.x >> 6;
    const int b_base = (blockIdx.x * 4 + wave) * 64;
    char* lw = lds_raw + wave * (64 * 128);

    // ---- Phase 1: cooperative gather of 64 records into LDS ----
    // inst k: lane handles chunk (lane&7) of record r = 8k + (lane>>3)
    const int c = lane & 7;
    const int rhi = lane >> 3;           // 0..7
    #pragma unroll
    for (int k = 0; k < 8; ++k) {
        const int r = 8 * k + rhi;       // record index within wave's 64
        const int brow = b_base + r;
        int a = 0;
        if (brow < B) a = ann[brow];
        const f16x8 chunk = *reinterpret_cast<const f16x8*>(
            rec + (size_t)a * 64 + c * 8);
        // swizzled LDS placement: chunk c of record r at r*128 + ((c^(r&7))*16)
        *reinterpret_cast<f16x8*>(lw + r * 128 + ((c ^ (r & 7)) << 4)) = chunk;
    }
    __syncthreads();

    // ---- Phase 2: each lane consumes its own record (r = lane) ----
    const int b = b_base + lane;
    if (b >= B) return;

    const f32x4* epsv = reinterpret_cast<const f32x4*>(eps + (size_t)b * 8);
    const f32x4 e0 = __builtin_nontemporal_load(epsv);
    const f32x4 e1 = __builtin_nontemporal_load(epsv + 1);
    const float e[8] = {e0[0], e0[1], e0[2], e0[3], e1[0], e1[1], e1[2], e1[3]};

    f16x8 ch[7];
    #pragma unroll
    for (int cc = 0; cc < 7; ++cc) {
        ch[cc] = *reinterpret_cast<const f16x8*>(
            lw + lane * 128 + ((cc ^ (lane & 7)) << 4));
    }

    float z[8];
    #pragma unroll
    for (int i = 0; i < 8; ++i) z[i] = (float)ch[0][i];
    // rows 0..3: L[i][j] = ch[1 + (i>>1)][(i&1)*4 + j]
    #pragma unroll
    for (int i = 0; i < 4; ++i) {
        #pragma unroll
        for (int j = 0; j <= i; ++j)
            z[i] += (float)ch[1 + (i >> 1)][(i & 1) * 4 + j] * e[j];
    }
    // rows 4..7: L[i][j] = ch[3 + (i-4)][j]
    #pragma unroll
    for (int i = 4; i < 8; ++i) {
        #pragma unroll
        for (int j = 0; j <= i; ++j)
            z[i] += (float)ch[3 + (i - 4)][j] * e[j];
    }

    f32x4* outv = reinterpret_cast<f32x4*>(out + (size_t)b * 8);
    f32x4 o0 = {z[0], z[1], z[2], z[3]};
    f32x4 o1 = {z[4], z[5], z[6], z[7]};
    __builtin_nontemporal_store(o0, outv);
    __builtin_nontemporal_store(o1, outv + 1);
}

// ---- fallback: fp32 direct (if ws too small) ----
__global__ __launch_bounds__(256) void lv_kernel_f32(
    const int* __restrict__ ann,
    const float* __restrict__ mu,
    const float* __restrict__ L,
    const float* __restrict__ eps,
    float* __restrict__ out,
    int B)
{
    int b = blockIdx.x * blockDim.x + threadIdx.x;
    if (b >= B) return;
    const int a = ann[b];
    const f32x4* epsv = reinterpret_cast<const f32x4*>(eps + (size_t)b * 8);
    const f32x4 e0 = epsv[0];
    const f32x4 e1 = epsv[1];
    const float e[8] = {e0[0], e0[1], e0[2], e0[3], e1[0], e1[1], e1[2], e1[3]};
    const f32x4* muv = reinterpret_cast<const f32x4*>(mu + (size_t)a * 8);
    const f32x4 m0 = muv[0];
    const f32x4 m1 = muv[1];
    float z[8] = {m0[0], m0[1], m0[2], m0[3], m1[0], m1[1], m1[2], m1[3]};
    const f32x4* Lv = reinterpret_cast<const f32x4*>(L + (size_t)a * 64);
    #pragma unroll
    for (int i = 0; i < 4; ++i) {
        const f32x4 r0 = Lv[i * 2];
        #pragma unroll
        for (int j = 0; j <= i; ++j) z[i] += r0[j] * e[j];
    }
    #pragma unroll
    for (int i = 4; i < 8; ++i) {
        const f32x4 r0 = Lv[i * 2];
        const f32x4 r1 = Lv[i * 2 + 1];
        const float r[8] = {r0[0], r0[1], r0[2], r0[3], r1[0], r1[1], r1[2], r1[3]};
        #pragma unroll
        for (int j = 0; j <= i; ++j) z[i] += r[j] * e[j];
    }
    f32x4* outv = reinterpret_cast<f32x4*>(out + (size_t)b * 8);
    f32x4 o0 = {z[0], z[1], z[2], z[3]};
    f32x4 o1 = {z[4], z[5], z[6], z[7]};
    outv[0] = o0;
    outv[1] = o1;
}

extern "C" void kernel_launch(void* const* d_in, const int* in_sizes, int n_in,
                              void* d_out, int out_size, void* d_ws, size_t ws_size,
                              hipStream_t stream) {
    const int*   ann = (const int*)d_in[0];    // annotator [B]
    const float* mu  = (const float*)d_in[1];  // posterior_mu [A,8]
    const float* L   = (const float*)d_in[2];  // posterior_covtril [A,8,8]
    const float* eps = (const float*)d_in[3];  // eps [B,8]
    float* out = (float*)d_out;

    const int B = in_sizes[0];
    const int A = in_sizes[1] / 8;

    const size_t rec_bytes = (size_t)A * 64 * sizeof(_Float16);  // 8 MiB
    if (ws_size >= rec_bytes) {
        _Float16* rec = (_Float16*)d_ws;
        pack_kernel<<<(A + 255) / 256, 256, 0, stream>>>(mu, L, rec, A);
        // each block covers 256 batch rows (4 waves x 64)
        const int blocks = (B + 255) / 256;
        lv_kernel_coop<<<blocks, 256, 0, stream>>>(ann, rec, eps, out, B);
    } else {
        const int blocks = (B + 255) / 256;
        lv_kernel_f32<<<blocks, 256, 0, stream>>>(ann, mu, L, eps, out, B);
    }
}